// Round 11
// baseline (185.465 us; speedup 1.0000x reference)
//
#include <hip/hip_runtime.h>

typedef float f2 __attribute__((ext_vector_type(2)));

#define N_QUBITS 5
#define DIM 32

// ---------- verified perm machinery (rounds 1/2/7/8/9/10) ----------
__host__ __device__ constexpr int cnot_apply(int i, int ctrl, int tgt) {
    const int pc = N_QUBITS - 1 - ctrl;
    const int pt = N_QUBITS - 1 - tgt;
    return i ^ (((i >> pc) & 1) << pt);
}
__host__ __device__ constexpr int layer_perm(int i, int r) {
    int idx = i;
    for (int q = N_QUBITS - 1; q >= 0; --q)
        idx = cnot_apply(idx, q, (q + r) % N_QUBITS);
    return idx;
}
__host__ __device__ constexpr int P1(int i) { return layer_perm(i, 1); }
__host__ __device__ constexpr int invP1(int p) {
    for (int l = 0; l < 32; ++l) if (P1(l) == p) return l;
    return 0;
}
// round-10 prob-read composition: slot p holds logical label invC(p)
__host__ __device__ constexpr int Cmap(int l) { return layer_perm(layer_perm(l, 2), 1); }
__host__ __device__ constexpr int invC(int p) {
    for (int l = 0; l < 32; ++l) if (Cmap(l) == p) return l;
    return 0;
}
// gate-q geometry under pi1-composed indexing (constexpr-derived, no hand tables)
__host__ __device__ constexpr int gmask(int q) { return P1(16 >> q); }                       // phys butterfly mask
__host__ __device__ constexpr int role0(int q, int j) { return (invP1(j) >> (4 - q)) & 1; }  // b-role at h=0
__host__ __device__ constexpr int hflip(int q) { return (invP1(16) >> (4 - q)) & 1; }        // role flips with h?

__device__ inline f2 shx(f2 v) {   // exchange with lane^32 (partner half)
    f2 r;
    r.x = __shfl_xor(v.x, 32, 64);
    r.y = __shfl_xor(v.y, 32, 64);
    return r;
}

// Split-state: thread (li, h) holds physical slots {j + 16h : j=0..15} of batch
// pair (b0,b1) in SoA f2 (x = b0, y = b1). 2 threads/batch-pair, 4 waves/SIMD.
__global__ __launch_bounds__(256, 4) void vqc_kernel(
    const float* __restrict__ x,      // (B, 5)
    const float* __restrict__ w,      // (2, 5, 3)
    const float* __restrict__ fc_w,   // (8, 5)
    const float* __restrict__ fc_b,   // (8,)
    float* __restrict__ out,          // (B, 8)
    int Btot)
{
    // ---- block-uniform gate precompute (round-10 verbatim preamble) ----
    __shared__ float s_g0[N_QUBITS][8];   // layer 0: 8 raw coeffs
    __shared__ float s_g1[N_QUBITS][4];   // layer 1: c00r,c00i,c01r,c01i
    __shared__ float s_fc_w[40];
    __shared__ float s_fc_b[8];

    const int t = threadIdx.x;
    if (t < 2 * N_QUBITS) {
        const float phi = w[t * 3 + 0];
        const float th  = w[t * 3 + 1];
        const float om  = w[t * 3 + 2];
        float s, c;   sincosf(0.5f * th, &s, &c);
        float sp, cp; sincosf(0.5f * (phi + om), &sp, &cp);
        float sm, cm; sincosf(0.5f * (phi - om), &sm, &cm);
        const float g00r =  cp * c, g00i = -sp * c;
        const float g01r = -cm * s, g01i = -sm * s;
        const float g10r =  cm * s, g10i = -sm * s;
        const float g11r =  cp * c, g11i =  sp * c;
        if (t < N_QUBITS) {
            s_g0[t][0] = g00r; s_g0[t][1] = g00i;
            s_g0[t][2] = g01r; s_g0[t][3] = g01i;
            s_g0[t][4] = g10r; s_g0[t][5] = g10i;
            s_g0[t][6] = g11r; s_g0[t][7] = g11i;
        } else {
            const int q = t - N_QUBITS;
            s_g1[q][0] = g00r; s_g1[q][1] = g00i;
            s_g1[q][2] = g01r; s_g1[q][3] = g01i;
        }
    } else if (t >= 16 && t < 56) {
        s_fc_w[t - 16] = fc_w[t - 16];
    } else if (t >= 56 && t < 64) {
        s_fc_b[t - 56] = fc_b[t - 56];
    }
    __syncthreads();

    const int lane = t & 63;
    const int li   = lane & 31;
    const int h    = lane >> 5;           // which physical half (bit4) this thread owns
    const int wv   = t >> 6;
    const int bp   = blockIdx.x * 128 + wv * 32 + li;   // batch-pair index
    const int b0   = bp;
    const int b1   = bp + (Btot >> 1);    // Btot/2 = 131072, exact grid: no guards

    const float* xp0 = x + (size_t)b0 * 5;
    const float* xp1 = x + (size_t)b1 * 5;

    // ---- build: post-layer-0 product state, local 16 slots ----
    // v formulas round-9/10-verified: v0 = g00*c + g01*(-is), v1 = g10*c + g11*(-is)
    f2 sre[16], sim[16];
    {
        float s0, c0, s1, c1;
        __sincosf(0.5f * xp0[0], &s0, &c0);
        __sincosf(0.5f * xp1[0], &s1, &c1);
        const f2 cc = f2{c0, c1}, ss = f2{s0, s1};
        const f2 a0re = s_g0[0][0] * cc + s_g0[0][3] * ss;
        const f2 a0im = s_g0[0][1] * cc - s_g0[0][2] * ss;
        const f2 a1re = s_g0[0][4] * cc + s_g0[0][7] * ss;
        const f2 a1im = s_g0[0][5] * cc - s_g0[0][6] * ss;
        sre[0] = h ? a1re : a0re;         // qubit-0 factor = my half's component
        sim[0] = h ? a1im : a0im;
    }
#pragma unroll
    for (int q = 1; q < N_QUBITS; ++q) {
        float s0, c0, s1, c1;
        __sincosf(0.5f * xp0[q], &s0, &c0);
        __sincosf(0.5f * xp1[q], &s1, &c1);
        const f2 cc = f2{c0, c1}, ss = f2{s0, s1};
        const f2 v0re = s_g0[q][0] * cc + s_g0[q][3] * ss;
        const f2 v0im = s_g0[q][1] * cc - s_g0[q][2] * ss;
        const f2 v1re = s_g0[q][4] * cc + s_g0[q][7] * ss;
        const f2 v1im = s_g0[q][5] * cc - s_g0[q][6] * ss;
        const int stride = 1 << (4 - q);
#pragma unroll
        for (int k = 0; k < (1 << (q - 1)); ++k) {
            const int m = k * (stride << 1);
            const f2 are = sre[m], aim = sim[m];
            sre[m + stride] = v1re * are - v1im * aim;
            sim[m + stride] = v1re * aim + v1im * are;
            sre[m]          = v0re * are - v0im * aim;
            sim[m]          = v0re * aim + v0im * are;
        }
    }

    // ---- layer 1: 5 gates, pi1-composed (round-10 butterfly algebra) ----
    // unified form: role sigma in {+1(a),-1(b)}: signs apply to c00i and c01r only.
    // role(j,h) = role0(q,j) ^ (h & hflip(q)); h-part folded into _e coeffs.
#pragma unroll
    for (int q = 0; q < N_QUBITS; ++q) {
        const float c00r = s_g1[q][0], c00i = s_g1[q][1];
        const float c01r = s_g1[q][2], c01i = s_g1[q][3];
        const bool  hf   = hflip(q);                    // constexpr
        const float c00i_e = (hf && h) ? -c00i : c00i;  // folds away when hf=0
        const float c01r_e = (hf && h) ? -c01r : c01r;
        const int   m  = gmask(q);                      // constexpr
        const int   ml = m & 15;
        const int   hb = (ml >= 8) ? 8 : (ml >= 4) ? 4 : (ml >= 2) ? 2 : 1;

        if (m >> 4) {
            // cross gate: my slot k pairs with partner's slot k^ml (other half).
            // groups {j, j^ml} (j<8): mutual shfl of originals, then update both.
#pragma unroll
            for (int j = 0; j < 8; ++j) {
                const int wsl = j ^ ml;
                const f2 ojre = shx(sre[j]);     // partner st[j]   -> for my slot wsl
                const f2 ojim = shx(sim[j]);
                const f2 owre = shx(sre[wsl]);   // partner st[wsl] -> for my slot j
                const f2 owim = shx(sim[wsl]);
                {
                    const float S = role0(q, j) ? -1.f : 1.f;
                    const f2 mr = sre[j], mi = sim[j];
                    sre[j] = c00r * mr - (S * c00i_e) * mi + (S * c01r_e) * owre - c01i * owim;
                    sim[j] = c00r * mi + (S * c00i_e) * mr + (S * c01r_e) * owim + c01i * owre;
                }
                {
                    const float S = role0(q, wsl) ? -1.f : 1.f;
                    const f2 mr = sre[wsl], mi = sim[wsl];
                    sre[wsl] = c00r * mr - (S * c00i_e) * mi + (S * c01r_e) * ojre - c01i * ojim;
                    sim[wsl] = c00r * mi + (S * c00i_e) * mr + (S * c01r_e) * ojim + c01i * ojre;
                }
            }
        } else {
            // local gate: pairs (j, j^ml) within my half
#pragma unroll
            for (int j = 0; j < 16; ++j) {
                if ((j & hb) != 0) continue;            // compile-time filter
                const int wsl = j ^ ml;
                const f2 ar = sre[j],   ai = sim[j];
                const f2 br = sre[wsl], bi = sim[wsl];
                const float Sj = role0(q, j)   ? -1.f : 1.f;
                const float Sw = role0(q, wsl) ? -1.f : 1.f;
                sre[j]   = c00r * ar - (Sj * c00i_e) * ai + (Sj * c01r_e) * br - c01i * bi;
                sim[j]   = c00r * ai + (Sj * c00i_e) * ar + (Sj * c01r_e) * bi + c01i * br;
                sre[wsl] = c00r * br - (Sw * c00i_e) * bi + (Sw * c01r_e) * ar - c01i * ai;
                sim[wsl] = c00r * bi + (Sw * c00i_e) * br + (Sw * c01r_e) * ai + c01i * ar;
            }
        }
    }

    // ---- probs ----
    f2 pr[16];
#pragma unroll
    for (int j = 0; j < 16; ++j) pr[j] = sre[j] * sre[j] + sim[j] * sim[j];

    // ---- expvals: label(j,h) = invC(j) ^ (h ? invC(16) : 0)  [linear] ----
    // partial_b = (+/-)(h,K_b) * sum_j (-1)^{bit_b(invC(j))} pr[j]; merge via shfl.
    f2 ev[N_QUBITS];
    const int K = invC(16);
#pragma unroll
    for (int b = 0; b < 5; ++b) {
        f2 T = f2{0.f, 0.f};
#pragma unroll
        for (int j = 0; j < 16; ++j) {
            if ((invC(j) >> b) & 1) T -= pr[j]; else T += pr[j];
        }
        const f2 Tp = (((K >> b) & 1) && h) ? -T : T;
        f2 Ts;
        Ts.x = __shfl_xor(Tp.x, 32, 64);
        Ts.y = __shfl_xor(Tp.y, 32, 64);
        ev[4 - b] = Tp + Ts;    // ev[q] uses logical bit 4-q
    }

    // ---- FC: thread (li,h) -> out[b][4h..4h+3] for both batches ----
    f2 o[4];
#pragma unroll
    for (int jj = 0; jj < 4; ++jj) {
        const int j = 4 * h + jj;
        f2 acc = f2{s_fc_b[j], s_fc_b[j]};
#pragma unroll
        for (int q = 0; q < 5; ++q) acc += ev[q] * s_fc_w[j * 5 + q];
        o[jj] = acc;
    }
    *(float4*)(out + (size_t)b0 * 8 + 4 * h) = make_float4(o[0].x, o[1].x, o[2].x, o[3].x);
    *(float4*)(out + (size_t)b1 * 8 + 4 * h) = make_float4(o[0].y, o[1].y, o[2].y, o[3].y);
}

extern "C" void kernel_launch(void* const* d_in, const int* in_sizes, int n_in,
                              void* d_out, int out_size, void* d_ws, size_t ws_size,
                              hipStream_t stream) {
    const float* x    = (const float*)d_in[0];
    const float* w    = (const float*)d_in[1];
    const float* fc_w = (const float*)d_in[2];
    const float* fc_b = (const float*)d_in[3];
    float* out = (float*)d_out;

    const int Btot = in_sizes[0] / N_QUBITS;        // 262144
    const int grid = (Btot / 2 + 127) / 128;        // 1024 blocks, exact
    hipLaunchKernelGGL(vqc_kernel, dim3(grid), dim3(256), 0, stream,
                       x, w, fc_w, fc_b, out, Btot);
}

// Round 12
// 17.975 us; speedup vs baseline: 10.3178x; 10.3178x over previous
//
#include <hip/hip_runtime.h>

typedef float f2 __attribute__((ext_vector_type(2)));

#define N_QUBITS 5
#define DIM 32

// ---------- verified perm machinery (rounds 1/2/7-11) ----------
__host__ __device__ constexpr int cnot_apply(int i, int ctrl, int tgt) {
    const int pc = N_QUBITS - 1 - ctrl;
    const int pt = N_QUBITS - 1 - tgt;
    return i ^ (((i >> pc) & 1) << pt);
}
__host__ __device__ constexpr int layer_perm(int i, int r) {
    int idx = i;
    for (int q = N_QUBITS - 1; q >= 0; --q)
        idx = cnot_apply(idx, q, (q + r) % N_QUBITS);
    return idx;
}
__host__ __device__ constexpr int P1(int i) { return layer_perm(i, 1); }
__host__ __device__ constexpr int invP1(int p) {
    for (int l = 0; l < 32; ++l) if (P1(l) == p) return l;
    return 0;
}
__host__ __device__ constexpr int Cmap(int l) { return layer_perm(layer_perm(l, 2), 1); }
__host__ __device__ constexpr int invC(int p) {
    for (int l = 0; l < 32; ++l) if (Cmap(l) == p) return l;
    return 0;
}
__host__ __device__ constexpr int gmask(int q) { return P1(16 >> q); }
__host__ __device__ constexpr int hflip(int q) { return (invP1(16) >> (4 - q)) & 1; }
// bit j (j=0..15) = role of local slot j at h=0 for gate q
__host__ __device__ constexpr int role_mask(int q) {
    int m = 0;
    for (int j = 0; j < 16; ++j) m |= ((invP1(j) >> (4 - q)) & 1) << j;
    return m;
}
// bit j = bit b of logical label of local slot j (h=0)
__host__ __device__ constexpr int sgn_mask(int b) {
    int m = 0;
    for (int j = 0; j < 16; ++j) m |= ((invC(j) >> b) & 1) << j;
    return m;
}

__device__ __forceinline__ f2 shx(f2 v) {   // exchange with lane^32
    f2 r;
    r.x = __shfl_xor(v.x, 32, 64);
    r.y = __shfl_xor(v.y, 32, 64);
    return r;
}

// ---- one layer-1 gate, all geometry as compile-time constants ----
// numeric formulas verbatim from round-11 (PASS-verified)
template<int Q>
__device__ __forceinline__ void apply_gate(f2 (&sre)[16], f2 (&sim)[16],
                                           float c00r, float c00i,
                                           float c01r, float c01i, int h)
{
    constexpr int  M     = gmask(Q);
    constexpr int  ML    = M & 15;
    constexpr bool CROSS = (M >> 4) != 0;
    constexpr bool HF    = hflip(Q) != 0;
    constexpr int  R0    = role_mask(Q);

    const float c00i_e = (HF && h) ? -c00i : c00i;
    const float c01r_e = (HF && h) ? -c01r : c01r;

    if constexpr (CROSS) {
#pragma unroll
        for (int j = 0; j < 8; ++j) {
            const int wsl = j ^ ML;
            const f2 ojre = shx(sre[j]);     // partner st[j]   -> for my slot wsl
            const f2 ojim = shx(sim[j]);
            const f2 owre = shx(sre[wsl]);   // partner st[wsl] -> for my slot j
            const f2 owim = shx(sim[wsl]);
            {
                const float S = ((R0 >> j) & 1) ? -1.f : 1.f;
                const f2 mr = sre[j], mi = sim[j];
                sre[j] = c00r * mr - (S * c00i_e) * mi + (S * c01r_e) * owre - c01i * owim;
                sim[j] = c00r * mi + (S * c00i_e) * mr + (S * c01r_e) * owim + c01i * owre;
            }
            {
                const float S = ((R0 >> wsl) & 1) ? -1.f : 1.f;
                const f2 mr = sre[wsl], mi = sim[wsl];
                sre[wsl] = c00r * mr - (S * c00i_e) * mi + (S * c01r_e) * ojre - c01i * ojim;
                sim[wsl] = c00r * mi + (S * c00i_e) * mr + (S * c01r_e) * ojim + c01i * ojre;
            }
        }
    } else {
        constexpr int HB = (ML & 8) ? 8 : (ML & 4) ? 4 : (ML & 2) ? 2 : 1;
#pragma unroll
        for (int p = 0; p < 8; ++p) {
            const int j   = ((p & ~(HB - 1)) << 1) | (p & (HB - 1));  // bit HB clear
            const int wsl = j ^ ML;
            const f2 ar = sre[j],   ai = sim[j];
            const f2 br = sre[wsl], bi = sim[wsl];
            const float Sj = ((R0 >> j)   & 1) ? -1.f : 1.f;
            const float Sw = ((R0 >> wsl) & 1) ? -1.f : 1.f;
            sre[j]   = c00r * ar - (Sj * c00i_e) * ai + (Sj * c01r_e) * br - c01i * bi;
            sim[j]   = c00r * ai + (Sj * c00i_e) * ar + (Sj * c01r_e) * bi + c01i * br;
            sre[wsl] = c00r * br - (Sw * c00i_e) * bi + (Sw * c01r_e) * ar - c01i * ai;
            sim[wsl] = c00r * bi + (Sw * c00i_e) * br + (Sw * c01r_e) * ai + c01i * ar;
        }
    }
}

__global__ __launch_bounds__(256, 4) void vqc_kernel(
    const float* __restrict__ x,      // (B, 5)
    const float* __restrict__ w,      // (2, 5, 3)
    const float* __restrict__ fc_w,   // (8, 5)
    const float* __restrict__ fc_b,   // (8,)
    float* __restrict__ out,          // (B, 8)
    int Btot)
{
    __shared__ float s_g0[N_QUBITS][8];
    __shared__ float s_g1[N_QUBITS][4];
    __shared__ float s_fc_w[40];
    __shared__ float s_fc_b[8];

    const int t = threadIdx.x;
    if (t < 2 * N_QUBITS) {
        const float phi = w[t * 3 + 0];
        const float th  = w[t * 3 + 1];
        const float om  = w[t * 3 + 2];
        float s, c;   sincosf(0.5f * th, &s, &c);
        float sp, cp; sincosf(0.5f * (phi + om), &sp, &cp);
        float sm, cm; sincosf(0.5f * (phi - om), &sm, &cm);
        const float g00r =  cp * c, g00i = -sp * c;
        const float g01r = -cm * s, g01i = -sm * s;
        const float g10r =  cm * s, g10i = -sm * s;
        const float g11r =  cp * c, g11i =  sp * c;
        if (t < N_QUBITS) {
            s_g0[t][0] = g00r; s_g0[t][1] = g00i;
            s_g0[t][2] = g01r; s_g0[t][3] = g01i;
            s_g0[t][4] = g10r; s_g0[t][5] = g10i;
            s_g0[t][6] = g11r; s_g0[t][7] = g11i;
        } else {
            const int q = t - N_QUBITS;
            s_g1[q][0] = g00r; s_g1[q][1] = g00i;
            s_g1[q][2] = g01r; s_g1[q][3] = g01i;
        }
    } else if (t >= 16 && t < 56) {
        s_fc_w[t - 16] = fc_w[t - 16];
    } else if (t >= 56 && t < 64) {
        s_fc_b[t - 56] = fc_b[t - 56];
    }
    __syncthreads();

    const int lane = t & 63;
    const int li   = lane & 31;
    const int h    = lane >> 5;
    const int wv   = t >> 6;
    const int bp   = blockIdx.x * 128 + wv * 32 + li;
    const int b0   = bp;
    const int b1   = bp + (Btot >> 1);        // exact grid: no guards

    const float* xp0 = x + (size_t)b0 * 5;
    const float* xp1 = x + (size_t)b1 * 5;

    // ---- build: post-layer-0 product state, local 16 slots (round-11 verbatim) ----
    f2 sre[16], sim[16];
    {
        float s0, c0, s1, c1;
        __sincosf(0.5f * xp0[0], &s0, &c0);
        __sincosf(0.5f * xp1[0], &s1, &c1);
        const f2 cc = f2{c0, c1}, ss = f2{s0, s1};
        const f2 a0re = s_g0[0][0] * cc + s_g0[0][3] * ss;
        const f2 a0im = s_g0[0][1] * cc - s_g0[0][2] * ss;
        const f2 a1re = s_g0[0][4] * cc + s_g0[0][7] * ss;
        const f2 a1im = s_g0[0][5] * cc - s_g0[0][6] * ss;
        sre[0] = h ? a1re : a0re;
        sim[0] = h ? a1im : a0im;
    }
#pragma unroll
    for (int q = 1; q < N_QUBITS; ++q) {
        float s0, c0, s1, c1;
        __sincosf(0.5f * xp0[q], &s0, &c0);
        __sincosf(0.5f * xp1[q], &s1, &c1);
        const f2 cc = f2{c0, c1}, ss = f2{s0, s1};
        const f2 v0re = s_g0[q][0] * cc + s_g0[q][3] * ss;
        const f2 v0im = s_g0[q][1] * cc - s_g0[q][2] * ss;
        const f2 v1re = s_g0[q][4] * cc + s_g0[q][7] * ss;
        const f2 v1im = s_g0[q][5] * cc - s_g0[q][6] * ss;
        const int stride = 1 << (4 - q);
#pragma unroll
        for (int k = 0; k < (1 << (q - 1)); ++k) {
            const int m = k * (stride << 1);
            const f2 are = sre[m], aim = sim[m];
            sre[m + stride] = v1re * are - v1im * aim;
            sim[m + stride] = v1re * aim + v1im * are;
            sre[m]          = v0re * are - v0im * aim;
            sim[m]          = v0re * aim + v0im * are;
        }
    }

    // ---- layer 1: 5 gates, explicit template instantiation (no q-loop) ----
    apply_gate<0>(sre, sim, s_g1[0][0], s_g1[0][1], s_g1[0][2], s_g1[0][3], h);
    apply_gate<1>(sre, sim, s_g1[1][0], s_g1[1][1], s_g1[1][2], s_g1[1][3], h);
    apply_gate<2>(sre, sim, s_g1[2][0], s_g1[2][1], s_g1[2][2], s_g1[2][3], h);
    apply_gate<3>(sre, sim, s_g1[3][0], s_g1[3][1], s_g1[3][2], s_g1[3][3], h);
    apply_gate<4>(sre, sim, s_g1[4][0], s_g1[4][1], s_g1[4][2], s_g1[4][3], h);

    // ---- probs ----
    f2 pr[16];
#pragma unroll
    for (int j = 0; j < 16; ++j) pr[j] = sre[j] * sre[j] + sim[j] * sim[j];

    // ---- expvals: constexpr sign masks, shfl merge (round-11 algebra) ----
    f2 ev[N_QUBITS];
    constexpr int K = invC(16);
#define EV_BIT(BQ)                                                              \
    {                                                                           \
        constexpr int SG = sgn_mask(BQ);                                        \
        f2 T = f2{0.f, 0.f};                                                    \
        _Pragma("unroll")                                                       \
        for (int j = 0; j < 16; ++j) {                                          \
            if ((SG >> j) & 1) T -= pr[j]; else T += pr[j];                     \
        }                                                                       \
        const f2 Tp = (((K >> BQ) & 1) && h) ? -T : T;                          \
        f2 Ts;                                                                  \
        Ts.x = __shfl_xor(Tp.x, 32, 64);                                        \
        Ts.y = __shfl_xor(Tp.y, 32, 64);                                        \
        ev[4 - BQ] = Tp + Ts;                                                   \
    }
    EV_BIT(0) EV_BIT(1) EV_BIT(2) EV_BIT(3) EV_BIT(4)
#undef EV_BIT

    // ---- FC: thread (li,h) -> out[b][4h..4h+3] for both batches ----
    f2 o[4];
#pragma unroll
    for (int jj = 0; jj < 4; ++jj) {
        const int j = 4 * h + jj;
        f2 acc = f2{s_fc_b[j], s_fc_b[j]};
#pragma unroll
        for (int q = 0; q < 5; ++q) acc += ev[q] * s_fc_w[j * 5 + q];
        o[jj] = acc;
    }
    *(float4*)(out + (size_t)b0 * 8 + 4 * h) = make_float4(o[0].x, o[1].x, o[2].x, o[3].x);
    *(float4*)(out + (size_t)b1 * 8 + 4 * h) = make_float4(o[0].y, o[1].y, o[2].y, o[3].y);
}

extern "C" void kernel_launch(void* const* d_in, const int* in_sizes, int n_in,
                              void* d_out, int out_size, void* d_ws, size_t ws_size,
                              hipStream_t stream) {
    const float* x    = (const float*)d_in[0];
    const float* w    = (const float*)d_in[1];
    const float* fc_w = (const float*)d_in[2];
    const float* fc_b = (const float*)d_in[3];
    float* out = (float*)d_out;

    const int Btot = in_sizes[0] / N_QUBITS;        // 262144
    const int grid = (Btot / 2 + 127) / 128;        // 1024 blocks, exact
    hipLaunchKernelGGL(vqc_kernel, dim3(grid), dim3(256), 0, stream,
                       x, w, fc_w, fc_b, out, Btot);
}